// Round 11
// baseline (564.617 us; speedup 1.0000x reference)
//
#include <hip/hip_runtime.h>
#include <cstdint>
#include <cstddef>

#define N_NODES 50000
#define N_EDGES 400000
#define TOT_E   450000
#define G_GRAPHS 64
#define PB 2048  // partial blocks for bnstats (8 blocks/CU -> 32 waves/CU)
#define SCAN_B 98  // scan blocks of 512 (98*512 = 50176 >= N_NODES)

typedef unsigned short u16;
typedef unsigned int u32;
typedef unsigned char u8;
typedef __attribute__((ext_vector_type(8))) short s16x8;  // 8 bf16 (4 VGPRs)
typedef __attribute__((ext_vector_type(4))) float f32x4;  // MFMA accumulator
typedef __attribute__((ext_vector_type(2))) float f32x2;  // fp8 cvt result / pk_fma

__device__ __forceinline__ float b2f(u16 v) {
    union { u32 u; float f; } x; x.u = ((u32)v) << 16; return x.f;
}
__device__ __forceinline__ float lo2f(u32 u) {
    union { u32 u; float f; } x; x.u = u << 16; return x.f;
}
__device__ __forceinline__ float hi2f(u32 u) {
    union { u32 u; float f; } x; x.u = u & 0xffff0000u; return x.f;
}
__device__ __forceinline__ u16 f2b(float f) {
    union { float f; u32 u; } x; x.f = f;
    u32 r = x.u + 0x7fffu + ((x.u >> 16) & 1u);  // round-nearest-even
    return (u16)(r >> 16);
}
__device__ __forceinline__ u32 pack2(float a, float b) {
    return (u32)f2b(a) | ((u32)f2b(b) << 16);
}

// ---------------- graph build ----------------
__global__ void k_init_deg(int* __restrict__ deg) {
    int i = blockIdx.x * blockDim.x + threadIdx.x;
    if (i < N_NODES) deg[i] = 1;  // self loop
}

__global__ void k_hist(const int* __restrict__ ei, int* __restrict__ deg) {
    int e = blockIdx.x * blockDim.x + threadIdx.x;
    if (e < N_EDGES) atomicAdd(&deg[ei[N_EDGES + e]], 1);
}

// phase 1: block-local exclusive scan, block totals to bsum
__global__ void k_scan1(const int* __restrict__ deg, int* __restrict__ rowptr,
                        int* __restrict__ bsum) {
    __shared__ int buf[512];
    int tid = threadIdx.x;
    int i = blockIdx.x * 512 + tid;
    int v = (i < N_NODES) ? deg[i] : 0;
    buf[tid] = v;
    __syncthreads();
    for (int off = 1; off < 512; off <<= 1) {
        int t = (tid >= off) ? buf[tid - off] : 0;
        __syncthreads();
        buf[tid] += t;
        __syncthreads();
    }
    if (i < N_NODES) rowptr[i] = buf[tid] - v;  // block-local exclusive
    if (tid == 511) bsum[blockIdx.x] = buf[511];
}

// phase 2: exclusive scan of the 98 block sums (single 128-thread block)
__global__ void k_scan2(int* __restrict__ bsum) {
    __shared__ int buf[128];
    int tid = threadIdx.x;
    int v = (tid < SCAN_B) ? bsum[tid] : 0;
    buf[tid] = v;
    __syncthreads();
    for (int off = 1; off < 128; off <<= 1) {
        int t = (tid >= off) ? buf[tid - off] : 0;
        __syncthreads();
        buf[tid] += t;
        __syncthreads();
    }
    if (tid < SCAN_B) bsum[tid] = buf[tid] - v;  // exclusive
}

// phase 3: add block offsets; write cursor; rowptr[N] = TOT_E (statically known)
__global__ void k_scan3(int* __restrict__ rowptr, int* __restrict__ cursor,
                        const int* __restrict__ bsum) {
    int i = blockIdx.x * blockDim.x + threadIdx.x;
    if (i < N_NODES) {
        int v = rowptr[i] + bsum[i >> 9];
        rowptr[i] = v;
        cursor[i] = v;
    }
    if (i == 0) rowptr[N_NODES] = TOT_E;
}

__global__ void k_scatter(const int* __restrict__ ei, int* __restrict__ cursor,
                          int* __restrict__ col, int* __restrict__ cdst) {
    int e = blockIdx.x * blockDim.x + threadIdx.x;
    if (e < N_EDGES) {
        int s = ei[e], d = ei[N_EDGES + e];
        int p = atomicAdd(&cursor[d], 1);
        col[p] = s;
        cdst[p] = d;
    } else if (e < TOT_E) {
        int i = e - N_EDGES;
        int p = atomicAdd(&cursor[i], 1);
        col[p] = i;
        cdst[p] = i;
    }
}

// ---------------- W pack: fp32 [K][NO] -> bf16 B-fragment layout ----------------
// Same layout serves as the A-fragment of the swapped-operand GEMMs (A-frag and
// B-frag lane maps are identical: dim=lane&15, k=(lane>>4)*8+j).
template<int K, int NO>
__global__ void k_wpack(const float* __restrict__ W, u16* __restrict__ Bp) {
    constexpr int KC = (K + 31) / 32;
    constexpr int NT = NO / 16;
    int idx = blockIdx.x * 256 + threadIdx.x;
    if (idx >= KC * NT * 64) return;
    int lane = idx & 63;
    int t = (idx >> 6) % NT;
    int c = (idx >> 6) / NT;
    int n = t * 16 + (lane & 15);
    int kbase = c * 32 + (lane >> 4) * 8;
    u16 v[8];
#pragma unroll
    for (int j = 0; j < 8; j++) {
        int k = kbase + j;
        v[j] = (k < K) ? f2b(W[(size_t)k * NO + n]) : (u16)0;
    }
    *(uint4*)(Bp + (size_t)idx * 8) = *(const uint4*)v;
}

// ---------------- w-tilde: wts[h][k] = sum_c W[k][h*C+c]*as[h][c] (fp32) ------------
template<int K, int NO, int H, int C>
__global__ void k_wtilde(const float* __restrict__ W, const float* __restrict__ as,
                         const float* __restrict__ ad, float* __restrict__ wts,
                         float* __restrict__ wtd) {
    static_assert((C % 4) == 0, "C divisible by 4");
    int t = threadIdx.x;  // K*H == 256
    if (t >= K * H) return;
    int k = t / H, h = t - k * H;
    float s1a = 0.f, s1b = 0.f, s1c = 0.f, s1d = 0.f;
    float s2a = 0.f, s2b = 0.f, s2c = 0.f, s2d = 0.f;
    const float* wr = W + (size_t)k * NO + h * C;
    const float* ar = as + h * C;
    const float* dr = ad + h * C;
    for (int c = 0; c < C; c += 4) {
        float w0 = wr[c], w1 = wr[c + 1], w2 = wr[c + 2], w3 = wr[c + 3];
        s1a = fmaf(w0, ar[c], s1a);     s1b = fmaf(w1, ar[c + 1], s1b);
        s1c = fmaf(w2, ar[c + 2], s1c); s1d = fmaf(w3, ar[c + 3], s1d);
        s2a = fmaf(w0, dr[c], s2a);     s2b = fmaf(w1, dr[c + 1], s2b);
        s2c = fmaf(w2, dr[c + 2], s2c); s2d = fmaf(w3, dr[c + 3], s2d);
    }
    wts[h * K + k] = (s1a + s1b) + (s1c + s1d);
    wtd[h * K + k] = (s2a + s2b) + (s2c + s2d);
}

// ---------------- xform: xt = relu(x*sc+sh), bf16 in/out ----------------
template<int K>
__global__ void k_xform(const u16* __restrict__ X, const float* __restrict__ sc,
                        const float* __restrict__ sh, u16* __restrict__ Xt) {
    constexpr int NO2 = K / 2;
    int t = blockIdx.x * blockDim.x + threadIdx.x;
    if (t >= N_NODES * NO2) return;
    int w = t % NO2;
    u32 u = ((const u32*)X)[t];
    float2 scv = *(const float2*)&sc[2 * w];
    float2 shv = *(const float2*)&sh[2 * w];
    float a = fmaxf(lo2f(u) * scv.x + shv.x, 0.f);
    float b = fmaxf(hi2f(u) * scv.y + shv.y, 0.f);
    ((u32*)Xt)[t] = pack2(a, b);
}

// ---------------- scores from x-tilde: s = xt @ wt (per head) ----------------
template<int K, int H>
__global__ void k_scores_x(const u16* __restrict__ Xt, const float* __restrict__ wts,
                           const float* __restrict__ wtd, float* __restrict__ ssrc,
                           float* __restrict__ sdst) {
    int t = blockIdx.x * blockDim.x + threadIdx.x;
    if (t >= N_NODES * H) return;
    int i = t / H, h = t - i * H;
    const uint4* r = (const uint4*)(Xt + (size_t)i * K);
    const float4* ws = (const float4*)(wts + h * K);
    const float4* wd = (const float4*)(wtd + h * K);
    float s1 = 0.f, s2 = 0.f;
#pragma unroll
    for (int c8 = 0; c8 < K / 8; c8++) {
        uint4 u = r[c8];
        float v0 = lo2f(u.x), v1 = hi2f(u.x), v2 = lo2f(u.y), v3 = hi2f(u.y);
        float v4 = lo2f(u.z), v5 = hi2f(u.z), v6 = lo2f(u.w), v7 = hi2f(u.w);
        float4 aa = ws[c8 * 2], ab = ws[c8 * 2 + 1];
        float4 da = wd[c8 * 2], db = wd[c8 * 2 + 1];
        s1 = fmaf(v0, aa.x, fmaf(v1, aa.y, fmaf(v2, aa.z, fmaf(v3, aa.w, s1))));
        s1 = fmaf(v4, ab.x, fmaf(v5, ab.y, fmaf(v6, ab.z, fmaf(v7, ab.w, s1))));
        s2 = fmaf(v0, da.x, fmaf(v1, da.y, fmaf(v2, da.z, fmaf(v3, da.w, s2))));
        s2 = fmaf(v4, db.x, fmaf(v5, db.y, fmaf(v6, db.z, fmaf(v7, db.w, s2))));
    }
    ssrc[t] = s1;
    sdst[t] = s2;
}

// ---------------- x-aggregation: m[i][h][k] = sum_j alpha_ij[h] * xt[j][k] ----------
template<int H, int K>
__global__ void k_aggx(const u16* __restrict__ Xt, const float* __restrict__ ssrc,
                       const float* __restrict__ sdst, const int* __restrict__ rowptr,
                       const int* __restrict__ col, u16* __restrict__ M) {
    constexpr int WPR = K / 2;      // u32 words per x-row (8 or 16)
    constexpr int EPR = 64 / WPR;   // edges per load round (8 or 4)
    constexpr int Q = K / 4;        // lanes per head
    static_assert(H * K == 256, "m row must be 256 elems (4/lane)");
    int wid = (int)((blockIdx.x * blockDim.x + threadIdx.x) >> 6);
    int lane = threadIdx.x & 63;
    if (wid >= N_NODES) return;
    int hl = lane / Q;              // head for this lane (< H)
    int q = lane % Q;               // k-quad: k = 4q..4q+3
    int lslot = lane / WPR;         // which edge of the round this lane loads
    int lword = lane % WPR;         // which word of that edge's row
    float sd = (lane < H) ? sdst[(size_t)wid * H + lane] : 0.f;
    f32x2 acc01 = {0.f, 0.f}, acc23 = {0.f, 0.f};
    float z = 0.f;
    int beg = rowptr[wid], end = rowptr[wid + 1];
    for (int base = beg; base < end; base += 64) {
        int nmax = min(64, end - base);
        int myc = (base + lane < end) ? col[base + lane] : 0;
        int j = 0;
        for (; j + EPR <= nmax; j += EPR) {
            int ce = __shfl(myc, j + lslot);
            u32 g = *(const u32*)(Xt + (size_t)ce * K + lword * 2);
            int se[EPR];
#pragma unroll
            for (int e = 0; e < EPR; e++) se[e] = __shfl(myc, j + e);
            float w[EPR];
#pragma unroll
            for (int e = 0; e < EPR; e++) w[e] = 0.f;
            if (lane < H) {
#pragma unroll
                for (int e = 0; e < EPR; e++) {
                    float v = ssrc[(size_t)se[e] * H + lane] + sd;
                    v = (v > 0.f) ? v : 0.2f * v;
                    w[e] = __expf(v);
                    z += w[e];
                }
            }
#pragma unroll
            for (int e = 0; e < EPR; e++) {
                float al = __shfl(w[e], hl);
                u32 xa = __shfl(g, e * WPR + 2 * q);
                u32 xb = __shfl(g, e * WPR + 2 * q + 1);
                f32x2 al2 = {al, al};
                f32x2 xa2 = {lo2f(xa), hi2f(xa)};
                f32x2 xb2 = {lo2f(xb), hi2f(xb)};
                acc01 += xa2 * al2;
                acc23 += xb2 * al2;
            }
        }
        for (; j < nmax; j++) {
            int se = __shfl(myc, j);
            u32 g = *(const u32*)(Xt + (size_t)se * K + lword * 2);
            float w0 = 0.f;
            if (lane < H) {
                float v = ssrc[(size_t)se * H + lane] + sd;
                v = (v > 0.f) ? v : 0.2f * v;
                w0 = __expf(v);
                z += w0;
            }
            float al = __shfl(w0, hl);
            u32 xa = __shfl(g, 2 * q);
            u32 xb = __shfl(g, 2 * q + 1);
            f32x2 al2 = {al, al};
            f32x2 xa2 = {lo2f(xa), hi2f(xa)};
            f32x2 xb2 = {lo2f(xb), hi2f(xb)};
            acc01 += xa2 * al2;
            acc23 += xb2 * al2;
        }
    }
    float zk = __shfl(z, hl);
    float inv = 1.0f / (zk + 1e-16f);
    uint2 o;
    o.x = pack2(acc01.x * inv, acc01.y * inv);
    o.y = pack2(acc23.x * inv, acc23.y * inv);
    u32* orow = (u32*)(M + (size_t)wid * (H * K));
    *(uint2*)&orow[hl * WPR + 2 * q] = o;
}

// ---------------- block-diagonal MFMA GEMM (swapped operands, u64 stores) ----------
// mfma(Wfrag, xfrag): D col = node (lane&15), D row = out-col (quad*4+i) ->
// each lane packs 4 consecutive out-cols of ONE node row into one 8-B store.
template<int K, int NO, int C>
__global__ __launch_bounds__(256, 2)
void k_gemmd(const u16* __restrict__ M, const u16* __restrict__ Bp,
             const float* __restrict__ wb, u16* __restrict__ Y) {
    constexpr int NT = NO / 16;
    constexpr int HK = (NO / C) * K;  // 256
    int lane = threadIdx.x & 63;
    int wv = __builtin_amdgcn_readfirstlane((int)(threadIdx.x >> 6));
    int rbase = blockIdx.x * 64 + wv * 16;
    int m = lane & 15, quad = lane >> 4;
    int arow = rbase + m;
    bool rowok = arow < N_NODES;
    if (!rowok) arow = N_NODES - 1;  // clamp loads; stores guarded
    const u16* xr = M + (size_t)arow * HK;

    f32x4 acc[NT];
#pragma unroll
    for (int t = 0; t < NT; t++) {
        int h = (t * 16) / C;
        s16x8 a;
        if (K == 32 || quad < 2) {
            a = *(const s16x8*)(xr + h * K + quad * 8);
        } else {
#pragma unroll
            for (int j = 0; j < 8; j++) a[j] = 0;  // k >= K (W side is zero too)
        }
        s16x8 b = *(const s16x8*)(Bp + ((size_t)(t * 64 + lane)) * 8);
        f32x4 z4 = (f32x4){0.f, 0.f, 0.f, 0.f};
        acc[t] = __builtin_amdgcn_mfma_f32_16x16x32_bf16(b, a, z4, 0, 0, 0);
    }

#pragma unroll
    for (int t = 0; t < NT; t++) {
        int colb = t * 16 + quad * 4;
        float4 bv = *(const float4*)&wb[colb];
        if (rowok) {
            uint2 o;
            o.x = pack2(acc[t][0] + bv.x, acc[t][1] + bv.y);
            o.y = pack2(acc[t][2] + bv.z, acc[t][3] + bv.w);
            *(uint2*)(Y + (size_t)arow * NO + colb) = o;
        }
    }
}

// ---------------- MFMA GEMM (fp32 input, swapped operands): Y = X @ W, bf16 out -----
template<int K, int NO, bool XFORM>
__global__ __launch_bounds__(256, 2)
void k_gemm(const float* __restrict__ X, const u16* __restrict__ Bp,
            const float* __restrict__ scale, const float* __restrict__ shift,
            u16* __restrict__ Y) {
    constexpr int KC = (K + 31) / 32;
    constexpr int NT = NO / 16;
    int lane = threadIdx.x & 63;
    int wv = __builtin_amdgcn_readfirstlane((int)(threadIdx.x >> 6));
    int rbase = blockIdx.x * 64 + wv * 16;
    int m = lane & 15, quad = lane >> 4;
    int arow = rbase + m;
    bool rowok = arow < N_NODES;
    if (!rowok) arow = N_NODES - 1;  // clamp loads; stores guarded
    const float* xr = X + (size_t)arow * K;

    f32x4 acc[NT];
#pragma unroll
    for (int t = 0; t < NT; t++) acc[t] = (f32x4){0.f, 0.f, 0.f, 0.f};

    for (int c = 0; c < KC; c++) {
        int kbase = c * 32 + quad * 8;
        float xv[8];
        if (kbase < K) {
            float4 va = *(const float4*)&xr[kbase];
            float4 vb = *(const float4*)&xr[kbase + 4];
            xv[0] = va.x; xv[1] = va.y; xv[2] = va.z; xv[3] = va.w;
            xv[4] = vb.x; xv[5] = vb.y; xv[6] = vb.z; xv[7] = vb.w;
            if (XFORM) {
                float4 sa = *(const float4*)&scale[kbase];
                float4 sb = *(const float4*)&scale[kbase + 4];
                float4 ha = *(const float4*)&shift[kbase];
                float4 hb = *(const float4*)&shift[kbase + 4];
                xv[0] = fmaxf(xv[0] * sa.x + ha.x, 0.f);
                xv[1] = fmaxf(xv[1] * sa.y + ha.y, 0.f);
                xv[2] = fmaxf(xv[2] * sa.z + ha.z, 0.f);
                xv[3] = fmaxf(xv[3] * sa.w + ha.w, 0.f);
                xv[4] = fmaxf(xv[4] * sb.x + hb.x, 0.f);
                xv[5] = fmaxf(xv[5] * sb.y + hb.y, 0.f);
                xv[6] = fmaxf(xv[6] * sb.z + hb.z, 0.f);
                xv[7] = fmaxf(xv[7] * sb.w + hb.w, 0.f);
            }
        } else {
#pragma unroll
            for (int j = 0; j < 8; j++) xv[j] = 0.f;
        }
        s16x8 a;
#pragma unroll
        for (int j = 0; j < 8; j++) a[j] = (short)f2b(xv[j]);

        const u16* bp = Bp + (size_t)(c * NT) * 64 * 8;
#pragma unroll
        for (int t = 0; t < NT; t++) {
            s16x8 b = *(const s16x8*)(bp + ((size_t)(t * 64 + lane)) * 8);
            acc[t] = __builtin_amdgcn_mfma_f32_16x16x32_bf16(b, a, acc[t], 0, 0, 0);
        }
    }

#pragma unroll
    for (int t = 0; t < NT; t++) {
        int colb = t * 16 + quad * 4;
        if (rowok) {
            uint2 o;
            o.x = pack2(acc[t][0], acc[t][1]);
            o.y = pack2(acc[t][2], acc[t][3]);
            *(uint2*)(Y + (size_t)arow * NO + colb) = o;
        }
    }
}

// ---------------- MFMA GEMM (bf16 input, swapped operands): Y = xform(X) @ W (+wb) --
template<int K, int NO, bool XFORM, bool BIAS>
__global__ __launch_bounds__(256, 2)
void k_gemmb(const u16* __restrict__ X, const u16* __restrict__ Bp,
             const float* __restrict__ scale, const float* __restrict__ shift,
             const float* __restrict__ wb, u16* __restrict__ Y) {
    constexpr int KC = (K + 31) / 32;
    constexpr int NT = NO / 16;
    int lane = threadIdx.x & 63;
    int wv = __builtin_amdgcn_readfirstlane((int)(threadIdx.x >> 6));
    int rbase = blockIdx.x * 64 + wv * 16;
    int m = lane & 15, quad = lane >> 4;
    int arow = rbase + m;
    bool rowok = arow < N_NODES;
    if (!rowok) arow = N_NODES - 1;  // clamp loads; stores guarded
    const u32* xr = (const u32*)(X + (size_t)arow * K);

    f32x4 acc[NT];
#pragma unroll
    for (int t = 0; t < NT; t++) acc[t] = (f32x4){0.f, 0.f, 0.f, 0.f};

    for (int c = 0; c < KC; c++) {
        int kbase = c * 32 + quad * 8;
        s16x8 a;
        if (kbase < K) {
            uint4 w = *(const uint4*)&xr[kbase >> 1];
            if (XFORM) {
                float xv[8];
                xv[0] = lo2f(w.x); xv[1] = hi2f(w.x);
                xv[2] = lo2f(w.y); xv[3] = hi2f(w.y);
                xv[4] = lo2f(w.z); xv[5] = hi2f(w.z);
                xv[6] = lo2f(w.w); xv[7] = hi2f(w.w);
                float4 sa = *(const float4*)&scale[kbase];
                float4 sb = *(const float4*)&scale[kbase + 4];
                float4 ha = *(const float4*)&shift[kbase];
                float4 hb = *(const float4*)&shift[kbase + 4];
                xv[0] = fmaxf(xv[0] * sa.x + ha.x, 0.f);
                xv[1] = fmaxf(xv[1] * sa.y + ha.y, 0.f);
                xv[2] = fmaxf(xv[2] * sa.z + ha.z, 0.f);
                xv[3] = fmaxf(xv[3] * sa.w + ha.w, 0.f);
                xv[4] = fmaxf(xv[4] * sb.x + hb.x, 0.f);
                xv[5] = fmaxf(xv[5] * sb.y + hb.y, 0.f);
                xv[6] = fmaxf(xv[6] * sb.z + hb.z, 0.f);
                xv[7] = fmaxf(xv[7] * sb.w + hb.w, 0.f);
#pragma unroll
                for (int j = 0; j < 8; j++) a[j] = (short)f2b(xv[j]);
            } else {
                a = *(const s16x8*)&w;  // bf16 passthrough
            }
        } else {
#pragma unroll
            for (int j = 0; j < 8; j++) a[j] = 0;
        }

        const u16* bp = Bp + (size_t)(c * NT) * 64 * 8;
#pragma unroll
        for (int t = 0; t < NT; t++) {
            s16x8 b = *(const s16x8*)(bp + ((size_t)(t * 64 + lane)) * 8);
            acc[t] = __builtin_amdgcn_mfma_f32_16x16x32_bf16(b, a, acc[t], 0, 0, 0);
        }
    }

#pragma unroll
    for (int t = 0; t < NT; t++) {
        int colb = t * 16 + quad * 4;
        float4 bv = BIAS ? *(const float4*)&wb[colb]
                         : make_float4(0.f, 0.f, 0.f, 0.f);
        if (rowok) {
            uint2 o;
            o.x = pack2(acc[t][0] + bv.x, acc[t][1] + bv.y);
            o.y = pack2(acc[t][2] + bv.z, acc[t][3] + bv.w);
            *(uint2*)(Y + (size_t)arow * NO + colb) = o;
        }
    }
}

// ---------------- attention scores (bf16 input) + fp8 shadow-copy emit --------------
template<int H, int C>
__global__ void k_scores(const u16* __restrict__ Hm, const float* __restrict__ asrc,
                         const float* __restrict__ adst, float* __restrict__ ssrc,
                         float* __restrict__ sdst, u8* __restrict__ H8) {
    static_assert(C == 16, "fp8 emit assumes C==16");
    int t = blockIdx.x * blockDim.x + threadIdx.x;
    if (t >= N_NODES * H) return;
    int i = t / H, h = t - i * H;
    const uint4* row4 = (const uint4*)(Hm + (size_t)i * H * C + h * C);
    const float4* a4 = (const float4*)(asrc + h * C);
    const float4* d4 = (const float4*)(adst + h * C);
    float s1 = 0.f, s2 = 0.f;
    uint4 q8;
    u32* qw = (u32*)&q8;
#pragma unroll
    for (int c8 = 0; c8 < C / 8; c8++) {
        uint4 u = row4[c8];
        float v0 = lo2f(u.x), v1 = hi2f(u.x), v2 = lo2f(u.y), v3 = hi2f(u.y);
        float v4 = lo2f(u.z), v5 = hi2f(u.z), v6 = lo2f(u.w), v7 = hi2f(u.w);
        float4 aa = a4[c8 * 2], ab = a4[c8 * 2 + 1];
        float4 da = d4[c8 * 2], db = d4[c8 * 2 + 1];
        s1 = fmaf(v0, aa.x, fmaf(v1, aa.y, fmaf(v2, aa.z, fmaf(v3, aa.w, s1))));
        s1 = fmaf(v4, ab.x, fmaf(v5, ab.y, fmaf(v6, ab.z, fmaf(v7, ab.w, s1))));
        s2 = fmaf(v0, da.x, fmaf(v1, da.y, fmaf(v2, da.z, fmaf(v3, da.w, s2))));
        s2 = fmaf(v4, db.x, fmaf(v5, db.y, fmaf(v6, db.z, fmaf(v7, db.w, s2))));
        u32 qa = 0, qb = 0;
        qa = __builtin_amdgcn_cvt_pk_fp8_f32(v0, v1, qa, false);
        qa = __builtin_amdgcn_cvt_pk_fp8_f32(v2, v3, qa, true);
        qb = __builtin_amdgcn_cvt_pk_fp8_f32(v4, v5, qb, false);
        qb = __builtin_amdgcn_cvt_pk_fp8_f32(v6, v7, qb, true);
        qw[c8 * 2] = qa;
        qw[c8 * 2 + 1] = qb;
    }
    ssrc[t] = s1;
    sdst[t] = s2;
    *(uint4*)(H8 + (size_t)i * (H * C) + h * C) = q8;  // 16 fp8 = 16 B, aligned
}

// ---------------- fused edge-softmax + aggregation over fp8 h (layer 1) -------------
template<int H, int C>
__global__ void k_agg8(const u8* __restrict__ Hm8, const float* __restrict__ ssrc,
                       const float* __restrict__ sdst, const int* __restrict__ rowptr,
                       const int* __restrict__ col, const float* __restrict__ bias,
                       u16* __restrict__ out) {
    constexpr int HC = H * C;
    constexpr int W2 = HC / 8;            // uint2(8 fp8) words per row; active lanes
    static_assert(W2 <= 64, "row must fit 64 uint2");
    static_assert((C % 8) == 0, "8-col block must stay within one head");
    int wid = (int)((blockIdx.x * blockDim.x + threadIdx.x) >> 6);
    int lane = threadIdx.x & 63;
    if (wid >= N_NODES) return;
    int hl = (8 * lane) / C;              // head for this lane's 8 cols
    int gidx = (lane < W2) ? lane : 0;    // clamped -> loads stay unconditional
    float sd = (lane < H) ? sdst[(size_t)wid * H + lane] : 0.f;
    f32x2 acc01 = {0.f, 0.f}, acc23 = {0.f, 0.f};
    f32x2 acc45 = {0.f, 0.f}, acc67 = {0.f, 0.f};
    float z = 0.f;
    int beg = rowptr[wid], end = rowptr[wid + 1];
#define ACC8(gg, wk) { \
        f32x2 wv_ = {wk, wk}; \
        acc01 += __builtin_amdgcn_cvt_pk_f32_fp8(gg.x, false) * wv_; \
        acc23 += __builtin_amdgcn_cvt_pk_f32_fp8(gg.x, true) * wv_; \
        acc45 += __builtin_amdgcn_cvt_pk_f32_fp8(gg.y, false) * wv_; \
        acc67 += __builtin_amdgcn_cvt_pk_f32_fp8(gg.y, true) * wv_; }
    for (int base = beg; base < end; base += 64) {
        int nmax = min(64, end - base);
        int myc = (base + lane < end) ? col[base + lane] : 0;
        int j = 0;
        for (; j + 4 <= nmax; j += 4) {
            int s0 = __shfl(myc, j), s1 = __shfl(myc, j + 1);
            int s2 = __shfl(myc, j + 2), s3 = __shfl(myc, j + 3);
            uint2 g0 = ((const uint2*)(Hm8 + (size_t)s0 * HC))[gidx];
            uint2 g1 = ((const uint2*)(Hm8 + (size_t)s1 * HC))[gidx];
            uint2 g2 = ((const uint2*)(Hm8 + (size_t)s2 * HC))[gidx];
            uint2 g3 = ((const uint2*)(Hm8 + (size_t)s3 * HC))[gidx];
            float w0 = 0.f, w1 = 0.f, w2 = 0.f, w3 = 0.f;
            if (lane < H) {
                float v0 = ssrc[(size_t)s0 * H + lane] + sd;
                float v1 = ssrc[(size_t)s1 * H + lane] + sd;
                float v2 = ssrc[(size_t)s2 * H + lane] + sd;
                float v3 = ssrc[(size_t)s3 * H + lane] + sd;
                v0 = (v0 > 0.f) ? v0 : 0.2f * v0;
                v1 = (v1 > 0.f) ? v1 : 0.2f * v1;
                v2 = (v2 > 0.f) ? v2 : 0.2f * v2;
                v3 = (v3 > 0.f) ? v3 : 0.2f * v3;
                w0 = __expf(v0); w1 = __expf(v1);
                w2 = __expf(v2); w3 = __expf(v3);
                z += (w0 + w1) + (w2 + w3);
            }
            float wk0 = __shfl(w0, hl), wk1 = __shfl(w1, hl);
            float wk2 = __shfl(w2, hl), wk3 = __shfl(w3, hl);
            ACC8(g0, wk0)
            ACC8(g1, wk1)
            ACC8(g2, wk2)
            ACC8(g3, wk3)
        }
        for (; j < nmax; j++) {
            int s0 = __shfl(myc, j);
            uint2 g0 = ((const uint2*)(Hm8 + (size_t)s0 * HC))[gidx];
            float w0 = 0.f;
            if (lane < H) {
                float v = ssrc[(size_t)s0 * H + lane] + sd;
                v = (v > 0.f) ? v : 0.2f * v;
                w0 = __expf(v);
                z += w0;
            }
            float wk0 = __shfl(w0, hl);
            ACC8(g0, wk0)
        }
    }
#undef ACC8
    float zk = __shfl(z, hl);  // all lanes execute shfl
    if (lane < W2) {
        float inv = 1.0f / (zk + 1e-16f);
        const float4* b4 = (const float4*)(bias + 8 * lane);
        float4 ba = b4[0], bb = b4[1];
        uint4 o;
        o.x = pack2(fmaf(acc01.x, inv, ba.x), fmaf(acc01.y, inv, ba.y));
        o.y = pack2(fmaf(acc23.x, inv, ba.z), fmaf(acc23.y, inv, ba.w));
        o.z = pack2(fmaf(acc45.x, inv, bb.x), fmaf(acc45.y, inv, bb.y));
        o.w = pack2(fmaf(acc67.x, inv, bb.z), fmaf(acc67.y, inv, bb.w));
        ((uint4*)(out + (size_t)wid * HC))[lane] = o;
    }
}

// ---------------- batchnorm stats over bf16 input (u32-pair vectorized) -------------
template<int NO>
__global__ void k_bnstats(const u16* __restrict__ X, float* __restrict__ psum,
                          float* __restrict__ psumsq) {
    constexpr int NO2 = NO / 2;
    constexpr int RPS = (NO2 >= 256) ? 1 : ((255 + NO2) / NO2);
    constexpr int BS = NO2 * RPS;
    __shared__ float2 ls[BS], ls2[BS];
    int c2 = threadIdx.x % NO2;
    int rsub = threadIdx.x / NO2;
    constexpr int chunk = (N_NODES + PB - 1) / PB;
    int r0 = blockIdx.x * chunk;
    int r1 = min(N_NODES, r0 + chunk);
    float2 s = make_float2(0.f, 0.f), s2 = make_float2(0.f, 0.f);
    const u32* Xw = (const u32*)X;
#pragma unroll 4
    for (int r = r0 + rsub; r < r1; r += RPS) {
        u32 u = Xw[(size_t)r * NO2 + c2];
        float a = lo2f(u), b = hi2f(u);
        s.x += a; s.y += b;
        s2.x += a * a; s2.y += b * b;
    }
    if (RPS > 1) {
        ls[threadIdx.x] = s;
        ls2[threadIdx.x] = s2;
        __syncthreads();
        for (int off = BS / 2; off >= NO2; off >>= 1) {
            if (threadIdx.x < off) {
                ls[threadIdx.x].x += ls[threadIdx.x + off].x;
                ls[threadIdx.x].y += ls[threadIdx.x + off].y;
                ls2[threadIdx.x].x += ls2[threadIdx.x + off].x;
                ls2[threadIdx.x].y += ls2[threadIdx.x + off].y;
            }
            __syncthreads();
        }
        s = ls[threadIdx.x];
        s2 = ls2[threadIdx.x];
    }
    if (rsub == 0) {
        *(float2*)&psum[(size_t)blockIdx.x * NO + 2 * c2] = s;
        *(float2*)&psumsq[(size_t)blockIdx.x * NO + 2 * c2] = s2;
    }
}

// column-parallel final reduce over PB partials
__global__ void k_bnfinal(const float* __restrict__ psum, const float* __restrict__ psumsq,
                          const float* __restrict__ g, const float* __restrict__ be,
                          float* __restrict__ scale, float* __restrict__ shift, int NO) {
    __shared__ float s1[256], s2[256];
    int col = blockIdx.x;
    int tid = threadIdx.x;
    float a = 0.f, b = 0.f;
    for (int bk = tid; bk < PB; bk += 256) {
        a += psum[(size_t)bk * NO + col];
        b += psumsq[(size_t)bk * NO + col];
    }
    s1[tid] = a;
    s2[tid] = b;
    __syncthreads();
    for (int off = 128; off > 0; off >>= 1) {
        if (tid < off) {
            s1[tid] += s1[tid + off];
            s2[tid] += s2[tid + off];
        }
        __syncthreads();
    }
    if (tid == 0) {
        float mu = s1[0] / (float)N_NODES;
        float var = s2[0] / (float)N_NODES - mu * mu;
        float sc = g[col] * rsqrtf(var + 1e-5f);
        scale[col] = sc;
        shift[col] = be[col] - mu * sc;
    }
}

// ---------------- pooling (bf16 input, u32-pair vectorized) ----------------
__global__ void k_bhist(const int* __restrict__ batch, int* __restrict__ cnt) {
    __shared__ int h[G_GRAPHS];
    int tid = threadIdx.x;
    if (tid < G_GRAPHS) h[tid] = 0;
    __syncthreads();
    int i = blockIdx.x * blockDim.x + tid;
    if (i < N_NODES) atomicAdd(&h[batch[i]], 1);
    __syncthreads();
    if (tid < G_GRAPHS) atomicAdd(&cnt[tid], h[tid]);
}

__global__ void k_pool(const u16* __restrict__ X, const int* __restrict__ batch,
                       const float* __restrict__ sc, const float* __restrict__ sh,
                       float* __restrict__ pooled) {
    int t2 = threadIdx.x;  // 192 threads, each owns u32 pair (cols 2*t2, 2*t2+1)
    const int chunk = (N_NODES + gridDim.x - 1) / gridDim.x;
    int r0 = blockIdx.x * chunk;
    int r1 = min(N_NODES, r0 + chunk);
    if (r0 >= N_NODES) return;
    float2 scv = *(const float2*)&sc[2 * t2];
    float2 shv = *(const float2*)&sh[2 * t2];
    const u32* Xw = (const u32*)X;
    float2 acc = make_float2(0.f, 0.f);
    int cur = batch[r0];
    for (int r = r0; r < r1; r++) {
        int gid = batch[r];
        if (gid != cur) {
            atomicAdd(&pooled[(size_t)cur * 384 + 2 * t2], acc.x);
            atomicAdd(&pooled[(size_t)cur * 384 + 2 * t2 + 1], acc.y);
            acc = make_float2(0.f, 0.f);
            cur = gid;
        }
        u32 u = Xw[(size_t)r * 192 + t2];
        acc.x += fmaxf(lo2f(u) * scv.x + shv.x, 0.f);
        acc.y += fmaxf(hi2f(u) * scv.y + shv.y, 0.f);
    }
    atomicAdd(&pooled[(size_t)cur * 384 + 2 * t2], acc.x);
    atomicAdd(&pooled[(size_t)cur * 384 + 2 * t2 + 1], acc.y);
}

// wave-parallel classifier: one wave per (graph, class) output
__global__ void k_final(const float* __restrict__ pooled, const int* __restrict__ cnt,
                        const float* __restrict__ lwf, const float* __restrict__ lbf,
                        float* __restrict__ out) {
    int wid = (int)((blockIdx.x * blockDim.x + threadIdx.x) >> 6);
    int lane = threadIdx.x & 63;
    if (wid >= G_GRAPHS * 10) return;
    int g = wid / 10, c = wid - g * 10;
    float inv = 1.0f / fmaxf((float)cnt[g], 1.0f);
    float acc = 0.f;
    for (int k = lane; k < 384; k += 64)
        acc += pooled[(size_t)g * 384 + k] * lwf[k * 10 + c];
#pragma unroll
    for (int off = 32; off > 0; off >>= 1) acc += __shfl_xor(acc, off);
    if (lane == 0) out[wid] = acc * inv + lbf[c];
}

extern "C" void kernel_launch(void* const* d_in, const int* in_sizes, int n_in,
                              void* d_out, int out_size, void* d_ws, size_t ws_size,
                              hipStream_t stream) {
    const float* x    = (const float*)d_in[0];
    const int*   ei   = (const int*)d_in[1];
    const int*   batch= (const int*)d_in[2];
    const float* W1   = (const float*)d_in[3];
    const float* as1  = (const float*)d_in[4];
    const float* ad1  = (const float*)d_in[5];
    const float* b1   = (const float*)d_in[6];
    const float* g1   = (const float*)d_in[7];
    const float* be1  = (const float*)d_in[8];
    const float* lw1  = (const float*)d_in[9];
    const float* lb1  = (const float*)d_in[10];
    const float* gl1  = (const float*)d_in[11];
    const float* bel1 = (const float*)d_in[12];
    const float* W2   = (const float*)d_in[13];
    const float* as2  = (const float*)d_in[14];
    const float* ad2  = (const float*)d_in[15];
    const float* b2   = (const float*)d_in[16];
    const float* g2   = (const float*)d_in[17];
    const float* be2  = (const float*)d_in[18];
    const float* lw2  = (const float*)d_in[19];
    const float* lb2  = (const float*)d_in[20];
    const float* gl2  = (const float*)d_in[21];
    const float* bel2 = (const float*)d_in[22];
    const float* W3   = (const float*)d_in[23];
    const float* as3  = (const float*)d_in[24];
    const float* ad3  = (const float*)d_in[25];
    const float* b3   = (const float*)d_in[26];
    const float* g3   = (const float*)d_in[27];
    const float* be3  = (const float*)d_in[28];
    const float* lwf  = (const float*)d_in[29];
    const float* lbf  = (const float*)d_in[30];
    float* out = (float*)d_out;

    // ---- workspace carve ----
    char* p = (char*)d_ws;
    auto alloc = [&](size_t bytes) {
        char* r = p;
        p += (bytes + 255) & ~(size_t)255;
        return r;
    };
    int*   rowptr = (int*)alloc(4 * (size_t)(N_NODES + 1));
    int*   cursor = (int*)alloc(4 * (size_t)N_NODES);
    int*   deg    = (int*)alloc(4 * (size_t)N_NODES);
    int*   bsum   = (int*)alloc(4 * (size_t)(SCAN_B + 1));
    int*   col    = (int*)alloc(4 * (size_t)TOT_E);
    int*   cdst   = (int*)alloc(4 * (size_t)TOT_E);
    float* ssrc   = (float*)alloc(4 * (size_t)N_NODES * 20);
    float* sdst   = (float*)alloc(4 * (size_t)N_NODES * 20);
    u16*   hbuf   = (u16*)alloc(2 * (size_t)N_NODES * 512);
    u16*   obuf   = (u16*)alloc(2 * (size_t)N_NODES * 512);
    u16*   xbuf   = (u16*)alloc(2 * (size_t)N_NODES * 32);
    u16*   xtil   = (u16*)alloc(2 * (size_t)N_NODES * 32);
    u8*    hbuf8  = (u8*)alloc((size_t)N_NODES * 320);
    float* psum   = (float*)alloc(4 * (size_t)PB * 512);
    float* psumsq = (float*)alloc(4 * (size_t)PB * 512);
    float* scA    = (float*)alloc(4 * 512);
    float* shA    = (float*)alloc(4 * 512);
    float* scB    = (float*)alloc(4 * 64);
    float* shB    = (float*)alloc(4 * 64);
    float* wts    = (float*)alloc(4 * 256);
    float* wtd    = (float*)alloc(4 * 256);
    float* pooled = (float*)alloc(4 * (size_t)G_GRAPHS * 384);
    int*   cnt    = (int*)alloc(4 * G_GRAPHS);
    u16*   bp1    = (u16*)alloc(2 * (size_t)4 * 20 * 64 * 8);   // W1: KC=4,NT=20
    u16*   bp2    = (u16*)alloc(2 * (size_t)1 * 32 * 64 * 8);   // W2: KC=1,NT=32
    u16*   bp3    = (u16*)alloc(2 * (size_t)1 * 24 * 64 * 8);   // W3: KC=1,NT=24
    u16*   bpl1   = (u16*)alloc(2 * (size_t)10 * 1 * 64 * 8);   // lw1: KC=10,NT=1
    u16*   bpl2   = (u16*)alloc(2 * (size_t)16 * 2 * 64 * 8);   // lw2: KC=16,NT=2
    u16*   mbuf   = hbuf;  // m[N][256] bf16 aliases hbuf (free after layer 1)

    const int LB = (N_NODES + 63) / 64;   // 782 row-tiles for MFMA gemms

    // ---- graph build + W packs (reused by all 3 layers) ----
    k_init_deg<<<(N_NODES + 255) / 256, 256, 0, stream>>>(deg);
    k_hist<<<(N_EDGES + 255) / 256, 256, 0, stream>>>(ei, deg);
    k_scan1<<<SCAN_B, 512, 0, stream>>>(deg, rowptr, bsum);
    k_scan2<<<1, 128, 0, stream>>>(bsum);
    k_scan3<<<(N_NODES + 255) / 256, 256, 0, stream>>>(rowptr, cursor, bsum);
    k_scatter<<<(TOT_E + 255) / 256, 256, 0, stream>>>(ei, cursor, col, cdst);
    k_wpack<128, 320><<<20, 256, 0, stream>>>(W1, bp1);
    k_wpack<16, 512><<<8, 256, 0, stream>>>(W2, bp2);
    k_wpack<32, 384><<<6, 256, 0, stream>>>(W3, bp3);
    k_wpack<320, 16><<<3, 256, 0, stream>>>(lw1, bpl1);
    k_wpack<512, 32><<<8, 256, 0, stream>>>(lw2, bpl2);
    hipMemsetAsync(pooled, 0, 4 * (size_t)G_GRAPHS * 384 + 256, stream);  // pooled + cnt

    // ---- layer 1: GAT(128 -> 20x16) (h-gather path; fp8 shadow for the gather) ----
    k_gemm<128, 320, false><<<LB, 256, 0, stream>>>(x, bp1, nullptr, nullptr, hbuf);
    k_scores<20, 16><<<(N_NODES * 20 + 255) / 256, 256, 0, stream>>>(hbuf, as1, ad1, ssrc, sdst, hbuf8);
    k_agg8<20, 16><<<(N_NODES + 3) / 4, 256, 0, stream>>>(hbuf8, ssrc, sdst, rowptr, col, b1, obuf);
    k_bnstats<320><<<PB, 320, 0, stream>>>(obuf, psum, psumsq);
    k_bnfinal<<<320, 256, 0, stream>>>(psum, psumsq, g1, be1, scA, shA, 320);
    k_gemmb<320, 16, true, true><<<LB, 256, 0, stream>>>(obuf, bpl1, scA, shA, lb1, xbuf);
    k_bnstats<16><<<PB, 256, 0, stream>>>(xbuf, psum, psumsq);
    k_bnfinal<<<16, 256, 0, stream>>>(psum, psumsq, gl1, bel1, scB, shB, 16);

    // ---- layer 2: GAT(16 -> 16x32), aggregate-then-transform ----
    k_wtilde<16, 512, 16, 32><<<1, 256, 0, stream>>>(W2, as2, ad2, wts, wtd);
    k_xform<16><<<(N_NODES * 8 + 255) / 256, 256, 0, stream>>>(xbuf, scB, shB, xtil);
    k_scores_x<16, 16><<<(N_NODES * 16 + 255) / 256, 256, 0, stream>>>(xtil, wts, wtd, ssrc, sdst);
    k_aggx<16, 16><<<(N_NODES + 3) / 4, 256, 0, stream>>>(xtil, ssrc, sdst, rowptr, col, mbuf);
    k_gemmd<16, 512, 32><<<LB, 256, 0, stream>>>(mbuf, bp2, b2, obuf);
    k_bnstats<512><<<PB, 256, 0, stream>>>(obuf, psum, psumsq);
    k_bnfinal<<<512, 256, 0, stream>>>(psum, psumsq, g2, be2, scA, shA, 512);
    k_gemmb<512, 32, true, true><<<LB, 256, 0, stream>>>(obuf, bpl2, scA, shA, lb2, xbuf);
    k_bnstats<32><<<PB, 256, 0, stream>>>(xbuf, psum, psumsq);
    k_bnfinal<<<32, 256, 0, stream>>>(psum, psumsq, gl2, bel2, scB, shB, 32);

    // ---- layer 3: GAT(32 -> 8x48), aggregate-then-transform ----
    k_wtilde<32, 384, 8, 48><<<1, 256, 0, stream>>>(W3, as3, ad3, wts, wtd);
    k_xform<32><<<(N_NODES * 16 + 255) / 256, 256, 0, stream>>>(xbuf, scB, shB, xtil);
    k_scores_x<32, 8><<<(N_NODES * 8 + 255) / 256, 256, 0, stream>>>(xtil, wts, wtd, ssrc, sdst);
    k_aggx<8, 32><<<(N_NODES + 3) / 4, 256, 0, stream>>>(xtil, ssrc, sdst, rowptr, col, mbuf);
    k_gemmd<32, 384, 48><<<LB, 256, 0, stream>>>(mbuf, bp3, b3, obuf);
    k_bnstats<384><<<PB, 384, 0, stream>>>(obuf, psum, psumsq);
    k_bnfinal<<<384, 256, 0, stream>>>(psum, psumsq, g3, be3, scA, shA, 384);

    // ---- pool + classifier ----
    k_bhist<<<(N_NODES + 255) / 256, 256, 0, stream>>>(batch, cnt);
    k_pool<<<2048, 192, 0, stream>>>(obuf, batch, scA, shA, pooled);
    k_final<<<160, 256, 0, stream>>>(pooled, cnt, lwf, lbf, out);
}

// Round 12
// 527.600 us; speedup vs baseline: 1.0702x; 1.0702x over previous
//
#include <hip/hip_runtime.h>
#include <cstdint>
#include <cstddef>

#define N_NODES 50000
#define N_EDGES 400000
#define TOT_E   450000
#define G_GRAPHS 64
#define PB 2048  // partial blocks for bnstats (8 blocks/CU -> 32 waves/CU)
#define SCAN_B 98  // scan blocks of 512 (98*512 = 50176 >= N_NODES)
#define GDB 1563   // gemmd blocks: 6250 subtiles (3125 row-tiles x 2 col-halves) / 4

typedef unsigned short u16;
typedef unsigned int u32;
typedef unsigned char u8;
typedef __attribute__((ext_vector_type(8))) short s16x8;  // 8 bf16 (4 VGPRs)
typedef __attribute__((ext_vector_type(4))) float f32x4;  // MFMA accumulator
typedef __attribute__((ext_vector_type(2))) float f32x2;  // fp8 cvt result / pk_fma

__device__ __forceinline__ float b2f(u16 v) {
    union { u32 u; float f; } x; x.u = ((u32)v) << 16; return x.f;
}
__device__ __forceinline__ float lo2f(u32 u) {
    union { u32 u; float f; } x; x.u = u << 16; return x.f;
}
__device__ __forceinline__ float hi2f(u32 u) {
    union { u32 u; float f; } x; x.u = u & 0xffff0000u; return x.f;
}
__device__ __forceinline__ u16 f2b(float f) {
    union { float f; u32 u; } x; x.f = f;
    u32 r = x.u + 0x7fffu + ((x.u >> 16) & 1u);  // round-nearest-even
    return (u16)(r >> 16);
}
__device__ __forceinline__ u32 pack2(float a, float b) {
    return (u32)f2b(a) | ((u32)f2b(b) << 16);
}

// ---------------- graph build ----------------
__global__ void k_init_deg(int* __restrict__ deg) {
    int i = blockIdx.x * blockDim.x + threadIdx.x;
    if (i < N_NODES) deg[i] = 1;  // self loop
}

__global__ void k_hist(const int* __restrict__ ei, int* __restrict__ deg) {
    int e = blockIdx.x * blockDim.x + threadIdx.x;
    if (e < N_EDGES) atomicAdd(&deg[ei[N_EDGES + e]], 1);
}

// phase 1: block-local exclusive scan, block totals to bsum
__global__ void k_scan1(const int* __restrict__ deg, int* __restrict__ rowptr,
                        int* __restrict__ bsum) {
    __shared__ int buf[512];
    int tid = threadIdx.x;
    int i = blockIdx.x * 512 + tid;
    int v = (i < N_NODES) ? deg[i] : 0;
    buf[tid] = v;
    __syncthreads();
    for (int off = 1; off < 512; off <<= 1) {
        int t = (tid >= off) ? buf[tid - off] : 0;
        __syncthreads();
        buf[tid] += t;
        __syncthreads();
    }
    if (i < N_NODES) rowptr[i] = buf[tid] - v;  // block-local exclusive
    if (tid == 511) bsum[blockIdx.x] = buf[511];
}

// phase 2: exclusive scan of the 98 block sums (single 128-thread block)
__global__ void k_scan2(int* __restrict__ bsum) {
    __shared__ int buf[128];
    int tid = threadIdx.x;
    int v = (tid < SCAN_B) ? bsum[tid] : 0;
    buf[tid] = v;
    __syncthreads();
    for (int off = 1; off < 128; off <<= 1) {
        int t = (tid >= off) ? buf[tid - off] : 0;
        __syncthreads();
        buf[tid] += t;
        __syncthreads();
    }
    if (tid < SCAN_B) bsum[tid] = buf[tid] - v;  // exclusive
}

// phase 3: add block offsets; write cursor; rowptr[N] = TOT_E (statically known)
__global__ void k_scan3(int* __restrict__ rowptr, int* __restrict__ cursor,
                        const int* __restrict__ bsum) {
    int i = blockIdx.x * blockDim.x + threadIdx.x;
    if (i < N_NODES) {
        int v = rowptr[i] + bsum[i >> 9];
        rowptr[i] = v;
        cursor[i] = v;
    }
    if (i == 0) rowptr[N_NODES] = TOT_E;
}

__global__ void k_scatter(const int* __restrict__ ei, int* __restrict__ cursor,
                          int* __restrict__ col, int* __restrict__ cdst) {
    int e = blockIdx.x * blockDim.x + threadIdx.x;
    if (e < N_EDGES) {
        int s = ei[e], d = ei[N_EDGES + e];
        int p = atomicAdd(&cursor[d], 1);
        col[p] = s;
        cdst[p] = d;
    } else if (e < TOT_E) {
        int i = e - N_EDGES;
        int p = atomicAdd(&cursor[i], 1);
        col[p] = i;
        cdst[p] = i;
    }
}

// ---------------- W pack: fp32 [K][NO] -> bf16 B-fragment layout ----------------
template<int K, int NO>
__global__ void k_wpack(const float* __restrict__ W, u16* __restrict__ Bp) {
    constexpr int KC = (K + 31) / 32;
    constexpr int NT = NO / 16;
    int idx = blockIdx.x * 256 + threadIdx.x;
    if (idx >= KC * NT * 64) return;
    int lane = idx & 63;
    int t = (idx >> 6) % NT;
    int c = (idx >> 6) / NT;
    int n = t * 16 + (lane & 15);
    int kbase = c * 32 + (lane >> 4) * 8;
    u16 v[8];
#pragma unroll
    for (int j = 0; j < 8; j++) {
        int k = kbase + j;
        v[j] = (k < K) ? f2b(W[(size_t)k * NO + n]) : (u16)0;
    }
    *(uint4*)(Bp + (size_t)idx * 8) = *(const uint4*)v;
}

// ---------------- w-tilde: wts[h][k] = sum_c W[k][h*C+c]*as[h][c] (fp32) ------------
template<int K, int NO, int H, int C>
__global__ void k_wtilde(const float* __restrict__ W, const float* __restrict__ as,
                         const float* __restrict__ ad, float* __restrict__ wts,
                         float* __restrict__ wtd) {
    static_assert((C % 4) == 0, "C divisible by 4");
    int t = threadIdx.x;  // K*H == 256
    if (t >= K * H) return;
    int k = t / H, h = t - k * H;
    float s1a = 0.f, s1b = 0.f, s1c = 0.f, s1d = 0.f;
    float s2a = 0.f, s2b = 0.f, s2c = 0.f, s2d = 0.f;
    const float* wr = W + (size_t)k * NO + h * C;
    const float* ar = as + h * C;
    const float* dr = ad + h * C;
    for (int c = 0; c < C; c += 4) {
        float w0 = wr[c], w1 = wr[c + 1], w2 = wr[c + 2], w3 = wr[c + 3];
        s1a = fmaf(w0, ar[c], s1a);     s1b = fmaf(w1, ar[c + 1], s1b);
        s1c = fmaf(w2, ar[c + 2], s1c); s1d = fmaf(w3, ar[c + 3], s1d);
        s2a = fmaf(w0, dr[c], s2a);     s2b = fmaf(w1, dr[c + 1], s2b);
        s2c = fmaf(w2, dr[c + 2], s2c); s2d = fmaf(w3, dr[c + 3], s2d);
    }
    wts[h * K + k] = (s1a + s1b) + (s1c + s1d);
    wtd[h * K + k] = (s2a + s2b) + (s2c + s2d);
}

// ---------------- xform: xt = relu(x*sc+sh), bf16 in/out ----------------
template<int K>
__global__ void k_xform(const u16* __restrict__ X, const float* __restrict__ sc,
                        const float* __restrict__ sh, u16* __restrict__ Xt) {
    constexpr int NO2 = K / 2;
    int t = blockIdx.x * blockDim.x + threadIdx.x;
    if (t >= N_NODES * NO2) return;
    int w = t % NO2;
    u32 u = ((const u32*)X)[t];
    float2 scv = *(const float2*)&sc[2 * w];
    float2 shv = *(const float2*)&sh[2 * w];
    float a = fmaxf(lo2f(u) * scv.x + shv.x, 0.f);
    float b = fmaxf(hi2f(u) * scv.y + shv.y, 0.f);
    ((u32*)Xt)[t] = pack2(a, b);
}

// ---------------- scores from x-tilde: s = xt @ wt (per head) ----------------
template<int K, int H>
__global__ void k_scores_x(const u16* __restrict__ Xt, const float* __restrict__ wts,
                           const float* __restrict__ wtd, float* __restrict__ ssrc,
                           float* __restrict__ sdst) {
    int t = blockIdx.x * blockDim.x + threadIdx.x;
    if (t >= N_NODES * H) return;
    int i = t / H, h = t - i * H;
    const uint4* r = (const uint4*)(Xt + (size_t)i * K);
    const float4* ws = (const float4*)(wts + h * K);
    const float4* wd = (const float4*)(wtd + h * K);
    float s1 = 0.f, s2 = 0.f;
#pragma unroll
    for (int c8 = 0; c8 < K / 8; c8++) {
        uint4 u = r[c8];
        float v0 = lo2f(u.x), v1 = hi2f(u.x), v2 = lo2f(u.y), v3 = hi2f(u.y);
        float v4 = lo2f(u.z), v5 = hi2f(u.z), v6 = lo2f(u.w), v7 = hi2f(u.w);
        float4 aa = ws[c8 * 2], ab = ws[c8 * 2 + 1];
        float4 da = wd[c8 * 2], db = wd[c8 * 2 + 1];
        s1 = fmaf(v0, aa.x, fmaf(v1, aa.y, fmaf(v2, aa.z, fmaf(v3, aa.w, s1))));
        s1 = fmaf(v4, ab.x, fmaf(v5, ab.y, fmaf(v6, ab.z, fmaf(v7, ab.w, s1))));
        s2 = fmaf(v0, da.x, fmaf(v1, da.y, fmaf(v2, da.z, fmaf(v3, da.w, s2))));
        s2 = fmaf(v4, db.x, fmaf(v5, db.y, fmaf(v6, db.z, fmaf(v7, db.w, s2))));
    }
    ssrc[t] = s1;
    sdst[t] = s2;
}

// ---------------- x-aggregation: m[i][h][k] = sum_j alpha_ij[h] * xt[j][k] ----------
template<int H, int K>
__global__ void k_aggx(const u16* __restrict__ Xt, const float* __restrict__ ssrc,
                       const float* __restrict__ sdst, const int* __restrict__ rowptr,
                       const int* __restrict__ col, u16* __restrict__ M) {
    constexpr int WPR = K / 2;      // u32 words per x-row (8 or 16)
    constexpr int EPR = 64 / WPR;   // edges per load round (8 or 4)
    constexpr int Q = K / 4;        // lanes per head
    static_assert(H * K == 256, "m row must be 256 elems (4/lane)");
    int wid = (int)((blockIdx.x * blockDim.x + threadIdx.x) >> 6);
    int lane = threadIdx.x & 63;
    if (wid >= N_NODES) return;
    int hl = lane / Q;              // head for this lane (< H)
    int q = lane % Q;               // k-quad: k = 4q..4q+3
    int lslot = lane / WPR;         // which edge of the round this lane loads
    int lword = lane % WPR;         // which word of that edge's row
    float sd = (lane < H) ? sdst[(size_t)wid * H + lane] : 0.f;
    f32x2 acc01 = {0.f, 0.f}, acc23 = {0.f, 0.f};
    float z = 0.f;
    int beg = rowptr[wid], end = rowptr[wid + 1];
    for (int base = beg; base < end; base += 64) {
        int nmax = min(64, end - base);
        int myc = (base + lane < end) ? col[base + lane] : 0;
        int j = 0;
        for (; j + EPR <= nmax; j += EPR) {
            int ce = __shfl(myc, j + lslot);
            u32 g = *(const u32*)(Xt + (size_t)ce * K + lword * 2);
            int se[EPR];
#pragma unroll
            for (int e = 0; e < EPR; e++) se[e] = __shfl(myc, j + e);
            float w[EPR];
#pragma unroll
            for (int e = 0; e < EPR; e++) w[e] = 0.f;
            if (lane < H) {
#pragma unroll
                for (int e = 0; e < EPR; e++) {
                    float v = ssrc[(size_t)se[e] * H + lane] + sd;
                    v = (v > 0.f) ? v : 0.2f * v;
                    w[e] = __expf(v);
                    z += w[e];
                }
            }
#pragma unroll
            for (int e = 0; e < EPR; e++) {
                float al = __shfl(w[e], hl);
                u32 xa = __shfl(g, e * WPR + 2 * q);
                u32 xb = __shfl(g, e * WPR + 2 * q + 1);
                f32x2 al2 = {al, al};
                f32x2 xa2 = {lo2f(xa), hi2f(xa)};
                f32x2 xb2 = {lo2f(xb), hi2f(xb)};
                acc01 += xa2 * al2;
                acc23 += xb2 * al2;
            }
        }
        for (; j < nmax; j++) {
            int se = __shfl(myc, j);
            u32 g = *(const u32*)(Xt + (size_t)se * K + lword * 2);
            float w0 = 0.f;
            if (lane < H) {
                float v = ssrc[(size_t)se * H + lane] + sd;
                v = (v > 0.f) ? v : 0.2f * v;
                w0 = __expf(v);
                z += w0;
            }
            float al = __shfl(w0, hl);
            u32 xa = __shfl(g, 2 * q);
            u32 xb = __shfl(g, 2 * q + 1);
            f32x2 al2 = {al, al};
            f32x2 xa2 = {lo2f(xa), hi2f(xa)};
            f32x2 xb2 = {lo2f(xb), hi2f(xb)};
            acc01 += xa2 * al2;
            acc23 += xb2 * al2;
        }
    }
    float zk = __shfl(z, hl);
    float inv = 1.0f / (zk + 1e-16f);
    uint2 o;
    o.x = pack2(acc01.x * inv, acc01.y * inv);
    o.y = pack2(acc23.x * inv, acc23.y * inv);
    u32* orow = (u32*)(M + (size_t)wid * (H * K));
    *(uint2*)&orow[hl * WPR + 2 * q] = o;
}

// ---------------- block-diagonal MFMA GEMM + fused BN stats (col-split waves) -------
// Each wave owns a 16-row x NO/2-col subtile: 2x the waves of the 64-row scheme ->
// ~24 waves/CU of latency hiding (was 12). Stats: per-block LDS accumulation
// (atomicAdd; waves may share columns), one partial row per block, k_bnfinalg reduces.
template<int K, int NO, int C>
__global__ void k_gemmd(const u16* __restrict__ M, const u16* __restrict__ Bp,
                        const float* __restrict__ wb, u16* __restrict__ Y,
                        float* __restrict__ pbuf) {
    constexpr int NT = NO / 16;
    constexpr int TS = NT / 2;        // t-values per wave (col-half)
    constexpr int HK = (NO / C) * K;  // 256
    __shared__ float ls[2 * NO];
    int tid = threadIdx.x;
    for (int i = tid; i < 2 * NO; i += 256) ls[i] = 0.f;
    __syncthreads();
    int lane = tid & 63;
    int wv = __builtin_amdgcn_readfirstlane(tid >> 6);
    int sid = blockIdx.x * 4 + wv;    // subtile id
    int rt = sid >> 1, ch = sid & 1;  // row-tile, col-half
    int rbase = rt * 16;
    int m = lane & 15, quad = lane >> 4;
    bool tileok = rbase < N_NODES;    // rt < 3125 (rows 16-aligned: all valid)
    int arow = rbase + m;
    if (arow >= N_NODES) arow = N_NODES - 1;
    const u16* xr = M + (size_t)arow * HK;
    if (tileok) {
        for (int tt = 0; tt < TS; tt++) {
            int t = ch * TS + tt;
            int h = (t * 16) / C;
            s16x8 a;
            if (K == 32 || quad < 2) {
                a = *(const s16x8*)(xr + h * K + quad * 8);
            } else {
#pragma unroll
                for (int j = 0; j < 8; j++) a[j] = 0;  // k >= K (B side is zero too)
            }
            s16x8 b = *(const s16x8*)(Bp + ((size_t)(t * 64 + lane)) * 8);
            f32x4 z4 = (f32x4){0.f, 0.f, 0.f, 0.f};
            f32x4 acc = __builtin_amdgcn_mfma_f32_16x16x32_bf16(a, b, z4, 0, 0, 0);
            int colb = t * 16 + m;
            float bv = wb[colb];
            float s = 0.f, q = 0.f;
#pragma unroll
            for (int i = 0; i < 4; i++) {
                int grow = rbase + quad * 4 + i;  // always < N_NODES when tileok
                float v = acc[i] + bv;
                Y[(size_t)grow * NO + colb] = f2b(v);
                s += v;
                q += v * v;
            }
            s += __shfl_xor(s, 16); s += __shfl_xor(s, 32);
            q += __shfl_xor(q, 16); q += __shfl_xor(q, 32);
            if (quad == 0) {
                atomicAdd(&ls[colb], s);
                atomicAdd(&ls[NO + colb], q);
            }
        }
    }
    __syncthreads();
    float* dst = pbuf + (size_t)blockIdx.x * (2 * NO);
    for (int i = tid; i < 2 * NO; i += 256) dst[i] = ls[i];
}

// column-parallel reduce over NB per-block partial rows (fused-stat producers)
__global__ void k_bnfinalg(const float* __restrict__ pbuf, const float* __restrict__ g,
                           const float* __restrict__ be, float* __restrict__ scale,
                           float* __restrict__ shift, int NO, int NB) {
    __shared__ float s1[256], s2[256];
    int col = blockIdx.x;
    int tid = threadIdx.x;
    float a = 0.f, b = 0.f;
    for (int bk = tid; bk < NB; bk += 256) {
        a += pbuf[(size_t)bk * 2 * NO + col];
        b += pbuf[(size_t)bk * 2 * NO + NO + col];
    }
    s1[tid] = a;
    s2[tid] = b;
    __syncthreads();
    for (int off = 128; off > 0; off >>= 1) {
        if (tid < off) {
            s1[tid] += s1[tid + off];
            s2[tid] += s2[tid + off];
        }
        __syncthreads();
    }
    if (tid == 0) {
        float mu = s1[0] / (float)N_NODES;
        float var = s2[0] / (float)N_NODES - mu * mu;
        float sc = g[col] * rsqrtf(var + 1e-5f);
        scale[col] = sc;
        shift[col] = be[col] - mu * sc;
    }
}

// ---------------- MFMA GEMM (fp32 input): Y[N,NO] = xform(X)[N,K] @ W, bf16 out -----
template<int K, int NO, bool XFORM>
__global__ __launch_bounds__(256, 2)
void k_gemm(const float* __restrict__ X, const u16* __restrict__ Bp,
            const float* __restrict__ scale, const float* __restrict__ shift,
            u16* __restrict__ Y) {
    constexpr int KC = (K + 31) / 32;
    constexpr int NT = NO / 16;
    int lane = threadIdx.x & 63;
    int wv = __builtin_amdgcn_readfirstlane((int)(threadIdx.x >> 6));
    int rbase = blockIdx.x * 64 + wv * 16;
    int m = lane & 15, quad = lane >> 4;
    int arow = rbase + m;
    if (arow >= N_NODES) arow = N_NODES - 1;  // clamp; stores guarded
    const float* xr = X + (size_t)arow * K;

    f32x4 acc[NT];
#pragma unroll
    for (int t = 0; t < NT; t++) acc[t] = (f32x4){0.f, 0.f, 0.f, 0.f};

    for (int c = 0; c < KC; c++) {
        int kbase = c * 32 + quad * 8;
        float xv[8];
        if (kbase < K) {
            float4 va = *(const float4*)&xr[kbase];
            float4 vb = *(const float4*)&xr[kbase + 4];
            xv[0] = va.x; xv[1] = va.y; xv[2] = va.z; xv[3] = va.w;
            xv[4] = vb.x; xv[5] = vb.y; xv[6] = vb.z; xv[7] = vb.w;
            if (XFORM) {
                float4 sa = *(const float4*)&scale[kbase];
                float4 sb = *(const float4*)&scale[kbase + 4];
                float4 ha = *(const float4*)&shift[kbase];
                float4 hb = *(const float4*)&shift[kbase + 4];
                xv[0] = fmaxf(xv[0] * sa.x + ha.x, 0.f);
                xv[1] = fmaxf(xv[1] * sa.y + ha.y, 0.f);
                xv[2] = fmaxf(xv[2] * sa.z + ha.z, 0.f);
                xv[3] = fmaxf(xv[3] * sa.w + ha.w, 0.f);
                xv[4] = fmaxf(xv[4] * sb.x + hb.x, 0.f);
                xv[5] = fmaxf(xv[5] * sb.y + hb.y, 0.f);
                xv[6] = fmaxf(xv[6] * sb.z + hb.z, 0.f);
                xv[7] = fmaxf(xv[7] * sb.w + hb.w, 0.f);
            }
        } else {
#pragma unroll
            for (int j = 0; j < 8; j++) xv[j] = 0.f;
        }
        s16x8 a;
#pragma unroll
        for (int j = 0; j < 8; j++) a[j] = (short)f2b(xv[j]);

        const u16* bp = Bp + (size_t)(c * NT) * 64 * 8;
#pragma unroll
        for (int t = 0; t < NT; t++) {
            s16x8 b = *(const s16x8*)(bp + ((size_t)(t * 64 + lane)) * 8);
            acc[t] = __builtin_amdgcn_mfma_f32_16x16x32_bf16(a, b, acc[t], 0, 0, 0);
        }
    }

#pragma unroll
    for (int t = 0; t < NT; t++) {
        int colb = t * 16 + m;
#pragma unroll
        for (int i = 0; i < 4; i++) {
            int grow = rbase + quad * 4 + i;
            if (grow < N_NODES) Y[(size_t)grow * NO + colb] = f2b(acc[t][i]);
        }
    }
}

// ---------------- MFMA GEMM (bf16 input): Y[N,NO] = xform(X)[N,K] @ W (+wb), bf16 out
template<int K, int NO, bool XFORM, bool BIAS>
__global__ __launch_bounds__(256, 2)
void k_gemmb(const u16* __restrict__ X, const u16* __restrict__ Bp,
             const float* __restrict__ scale, const float* __restrict__ shift,
             const float* __restrict__ wb, u16* __restrict__ Y) {
    constexpr int KC = (K + 31) / 32;
    constexpr int NT = NO / 16;
    int lane = threadIdx.x & 63;
    int wv = __builtin_amdgcn_readfirstlane((int)(threadIdx.x >> 6));
    int rbase = blockIdx.x * 64 + wv * 16;
    int m = lane & 15, quad = lane >> 4;
    int arow = rbase + m;
    if (arow >= N_NODES) arow = N_NODES - 1;  // clamp; stores guarded
    const u32* xr = (const u32*)(X + (size_t)arow * K);

    f32x4 acc[NT];
#pragma unroll
    for (int t = 0; t < NT; t++) acc[t] = (f32x4){0.f, 0.f, 0.f, 0.f};

    for (int c = 0; c < KC; c++) {
        int kbase = c * 32 + quad * 8;
        s16x8 a;
        if (kbase < K) {
            uint4 w = *(const uint4*)&xr[kbase >> 1];
            if (XFORM) {
                float xv[8];
                xv[0] = lo2f(w.x); xv[1] = hi2f(w.x);
                xv[2] = lo2f(w.y); xv[3] = hi2f(w.y);
                xv[4] = lo2f(w.z); xv[5] = hi2f(w.z);
                xv[6] = lo2f(w.w); xv[7] = hi2f(w.w);
                float4 sa = *(const float4*)&scale[kbase];
                float4 sb = *(const float4*)&scale[kbase + 4];
                float4 ha = *(const float4*)&shift[kbase];
                float4 hb = *(const float4*)&shift[kbase + 4];
                xv[0] = fmaxf(xv[0] * sa.x + ha.x, 0.f);
                xv[1] = fmaxf(xv[1] * sa.y + ha.y, 0.f);
                xv[2] = fmaxf(xv[2] * sa.z + ha.z, 0.f);
                xv[3] = fmaxf(xv[3] * sa.w + ha.w, 0.f);
                xv[4] = fmaxf(xv[4] * sb.x + hb.x, 0.f);
                xv[5] = fmaxf(xv[5] * sb.y + hb.y, 0.f);
                xv[6] = fmaxf(xv[6] * sb.z + hb.z, 0.f);
                xv[7] = fmaxf(xv[7] * sb.w + hb.w, 0.f);
#pragma unroll
                for (int j = 0; j < 8; j++) a[j] = (short)f2b(xv[j]);
            } else {
                a = *(const s16x8*)&w;  // bf16 passthrough
            }
        } else {
#pragma unroll
            for (int j = 0; j < 8; j++) a[j] = 0;
        }

        const u16* bp = Bp + (size_t)(c * NT) * 64 * 8;
#pragma unroll
        for (int t = 0; t < NT; t++) {
            s16x8 b = *(const s16x8*)(bp + ((size_t)(t * 64 + lane)) * 8);
            acc[t] = __builtin_amdgcn_mfma_f32_16x16x32_bf16(a, b, acc[t], 0, 0, 0);
        }
    }

#pragma unroll
    for (int t = 0; t < NT; t++) {
        int colb = t * 16 + m;
        float bv = BIAS ? wb[colb] : 0.f;
#pragma unroll
        for (int i = 0; i < 4; i++) {
            int grow = rbase + quad * 4 + i;
            if (grow < N_NODES) Y[(size_t)grow * NO + colb] = f2b(acc[t][i] + bv);
        }
    }
}

// ---------------- attention scores (bf16 input) + fp8 shadow-copy emit --------------
template<int H, int C>
__global__ void k_scores(const u16* __restrict__ Hm, const float* __restrict__ asrc,
                         const float* __restrict__ adst, float* __restrict__ ssrc,
                         float* __restrict__ sdst, u8* __restrict__ H8) {
    static_assert(C == 16, "fp8 emit assumes C==16");
    int t = blockIdx.x * blockDim.x + threadIdx.x;
    if (t >= N_NODES * H) return;
    int i = t / H, h = t - i * H;
    const uint4* row4 = (const uint4*)(Hm + (size_t)i * H * C + h * C);
    const float4* a4 = (const float4*)(asrc + h * C);
    const float4* d4 = (const float4*)(adst + h * C);
    float s1 = 0.f, s2 = 0.f;
    uint4 q8;
    u32* qw = (u32*)&q8;
#pragma unroll
    for (int c8 = 0; c8 < C / 8; c8++) {
        uint4 u = row4[c8];
        float v0 = lo2f(u.x), v1 = hi2f(u.x), v2 = lo2f(u.y), v3 = hi2f(u.y);
        float v4 = lo2f(u.z), v5 = hi2f(u.z), v6 = lo2f(u.w), v7 = hi2f(u.w);
        float4 aa = a4[c8 * 2], ab = a4[c8 * 2 + 1];
        float4 da = d4[c8 * 2], db = d4[c8 * 2 + 1];
        s1 = fmaf(v0, aa.x, fmaf(v1, aa.y, fmaf(v2, aa.z, fmaf(v3, aa.w, s1))));
        s1 = fmaf(v4, ab.x, fmaf(v5, ab.y, fmaf(v6, ab.z, fmaf(v7, ab.w, s1))));
        s2 = fmaf(v0, da.x, fmaf(v1, da.y, fmaf(v2, da.z, fmaf(v3, da.w, s2))));
        s2 = fmaf(v4, db.x, fmaf(v5, db.y, fmaf(v6, db.z, fmaf(v7, db.w, s2))));
        u32 qa = 0, qb = 0;
        qa = __builtin_amdgcn_cvt_pk_fp8_f32(v0, v1, qa, false);
        qa = __builtin_amdgcn_cvt_pk_fp8_f32(v2, v3, qa, true);
        qb = __builtin_amdgcn_cvt_pk_fp8_f32(v4, v5, qb, false);
        qb = __builtin_amdgcn_cvt_pk_fp8_f32(v6, v7, qb, true);
        qw[c8 * 2] = qa;
        qw[c8 * 2 + 1] = qb;
    }
    ssrc[t] = s1;
    sdst[t] = s2;
    *(uint4*)(H8 + (size_t)i * (H * C) + h * C) = q8;  // 16 fp8 = 16 B, aligned
}

// ---------------- fused edge-softmax + aggregation over fp8 h (layer 1) -------------
template<int H, int C>
__global__ void k_agg8(const u8* __restrict__ Hm8, const float* __restrict__ ssrc,
                       const float* __restrict__ sdst, const int* __restrict__ rowptr,
                       const int* __restrict__ col, const float* __restrict__ bias,
                       u16* __restrict__ out) {
    constexpr int HC = H * C;
    constexpr int W2 = HC / 8;            // uint2(8 fp8) words per row; active lanes
    static_assert(W2 <= 64, "row must fit 64 uint2");
    static_assert((C % 8) == 0, "8-col block must stay within one head");
    int wid = (int)((blockIdx.x * blockDim.x + threadIdx.x) >> 6);
    int lane = threadIdx.x & 63;
    if (wid >= N_NODES) return;
    int hl = (8 * lane) / C;              // head for this lane's 8 cols
    int gidx = (lane < W2) ? lane : 0;    // clamped -> loads stay unconditional
    float sd = (lane < H) ? sdst[(size_t)wid * H + lane] : 0.f;
    f32x2 acc01 = {0.f, 0.f}, acc23 = {0.f, 0.f};
    f32x2 acc45 = {0.f, 0.f}, acc67 = {0.f, 0.f};
    float z = 0.f;
    int beg = rowptr[wid], end = rowptr[wid + 1];
#define ACC8(gg, wk) { \
        f32x2 wv_ = {wk, wk}; \
        acc01 += __builtin_amdgcn_cvt_pk_f32_fp8(gg.x, false) * wv_; \
        acc23 += __builtin_amdgcn_cvt_pk_f32_fp8(gg.x, true) * wv_; \
        acc45 += __builtin_amdgcn_cvt_pk_f32_fp8(gg.y, false) * wv_; \
        acc67 += __builtin_amdgcn_cvt_pk_f32_fp8(gg.y, true) * wv_; }
    for (int base = beg; base < end; base += 64) {
        int nmax = min(64, end - base);
        int myc = (base + lane < end) ? col[base + lane] : 0;
        int j = 0;
        for (; j + 4 <= nmax; j += 4) {
            int s0 = __shfl(myc, j), s1 = __shfl(myc, j + 1);
            int s2 = __shfl(myc, j + 2), s3 = __shfl(myc, j + 3);
            uint2 g0 = ((const uint2*)(Hm8 + (size_t)s0 * HC))[gidx];
            uint2 g1 = ((const uint2*)(Hm8 + (size_t)s1 * HC))[gidx];
            uint2 g2 = ((const uint2*)(Hm8 + (size_t)s2 * HC))[gidx];
            uint2 g3 = ((const uint2*)(Hm8 + (size_t)s3 * HC))[gidx];
            float w0 = 0.f, w1 = 0.f, w2 = 0.f, w3 = 0.f;
            if (lane < H) {
                float v0 = ssrc[(size_t)s0 * H + lane] + sd;
                float v1 = ssrc[(size_t)s1 * H + lane] + sd;
                float v2 = ssrc[(size_t)s2 * H + lane] + sd;
                float v3 = ssrc[(size_t)s3 * H + lane] + sd;
                v0 = (v0 > 0.f) ? v0 : 0.2f * v0;
                v1 = (v1 > 0.f) ? v1 : 0.2f * v1;
                v2 = (v2 > 0.f) ? v2 : 0.2f * v2;
                v3 = (v3 > 0.f) ? v3 : 0.2f * v3;
                w0 = __expf(v0); w1 = __expf(v1);
                w2 = __expf(v2); w3 = __expf(v3);
                z += (w0 + w1) + (w2 + w3);
            }
            float wk0 = __shfl(w0, hl), wk1 = __shfl(w1, hl);
            float wk2 = __shfl(w2, hl), wk3 = __shfl(w3, hl);
            ACC8(g0, wk0)
            ACC8(g1, wk1)
            ACC8(g2, wk2)
            ACC8(g3, wk3)
        }
        for (; j < nmax; j++) {
            int s0 = __shfl(myc, j);
            uint2 g0 = ((const uint2*)(Hm8 + (size_t)s0 * HC))[gidx];
            float w0 = 0.f;
            if (lane < H) {
                float v = ssrc[(size_t)s0 * H + lane] + sd;
                v = (v > 0.f) ? v : 0.2f * v;
                w0 = __expf(v);
                z += w0;
            }
            float wk0 = __shfl(w0, hl);
            ACC8(g0, wk0)
        }
    }
#undef ACC8
    float zk = __shfl(z, hl);  // all lanes execute shfl
    if (lane < W2) {
        float inv = 1.0f / (zk + 1e-16f);
        const float4* b4 = (const float4*)(bias + 8 * lane);
        float4 ba = b4[0], bb = b4[1];
        uint4 o;
        o.x = pack2(fmaf(acc01.x, inv, ba.x), fmaf(acc01.y, inv, ba.y));
        o.y = pack2(fmaf(acc23.x, inv, ba.z), fmaf(acc23.y, inv, ba.w));
        o.z = pack2(fmaf(acc45.x, inv, bb.x), fmaf(acc45.y, inv, bb.y));
        o.w = pack2(fmaf(acc67.x, inv, bb.z), fmaf(acc67.y, inv, bb.w));
        ((uint4*)(out + (size_t)wid * HC))[lane] = o;
    }
}

// ---------------- batchnorm stats over bf16 input (u32-pair vectorized) -------------
template<int NO>
__global__ void k_bnstats(const u16* __restrict__ X, float* __restrict__ psum,
                          float* __restrict__ psumsq) {
    constexpr int NO2 = NO / 2;
    constexpr int RPS = (NO2 >= 256) ? 1 : ((255 + NO2) / NO2);
    constexpr int BS = NO2 * RPS;
    __shared__ float2 ls[BS], ls2[BS];
    int c2 = threadIdx.x % NO2;
    int rsub = threadIdx.x / NO2;
    constexpr int chunk = (N_NODES + PB - 1) / PB;
    int r0 = blockIdx.x * chunk;
    int r1 = min(N_NODES, r0 + chunk);
    float2 s = make_float2(0.f, 0.f), s2 = make_float2(0.f, 0.f);
    const u32* Xw = (const u32*)X;
#pragma unroll 4
    for (int r = r0 + rsub; r < r1; r += RPS) {
        u32 u = Xw[(size_t)r * NO2 + c2];
        float a = lo2f(u), b = hi2f(u);
        s.x += a; s.y += b;
        s2.x += a * a; s2.y += b * b;
    }
    if (RPS > 1) {
        ls[threadIdx.x] = s;
        ls2[threadIdx.x] = s2;
        __syncthreads();
        for (int off = BS / 2; off >= NO2; off >>= 1) {
            if (threadIdx.x < off) {
                ls[threadIdx.x].x += ls[threadIdx.x + off].x;
                ls[threadIdx.x].y += ls[threadIdx.x + off].y;
                ls2[threadIdx.x].x += ls2[threadIdx.x + off].x;
                ls2[threadIdx.x].y += ls2[threadIdx.x + off].y;
            }
            __syncthreads();
        }
        s = ls[threadIdx.x];
        s2 = ls2[threadIdx.x];
    }
    if (rsub == 0) {
        *(float2*)&psum[(size_t)blockIdx.x * NO + 2 * c2] = s;
        *(float2*)&psumsq[(size_t)blockIdx.x * NO + 2 * c2] = s2;
    }
}

// column-parallel final reduce over PB partials (for standalone bnstats path)
__global__ void k_bnfinal(const float* __restrict__ psum, const float* __restrict__ psumsq,
                          const float* __restrict__ g, const float* __restrict__ be,
                          float* __restrict__ scale, float* __restrict__ shift, int NO) {
    __shared__ float s1[256], s2[256];
    int col = blockIdx.x;
    int tid = threadIdx.x;
    float a = 0.f, b = 0.f;
    for (int bk = tid; bk < PB; bk += 256) {
        a += psum[(size_t)bk * NO + col];
        b += psumsq[(size_t)bk * NO + col];
    }
    s1[tid] = a;
    s2[tid] = b;
    __syncthreads();
    for (int off = 128; off > 0; off >>= 1) {
        if (tid < off) {
            s1[tid] += s1[tid + off];
            s2[tid] += s2[tid + off];
        }
        __syncthreads();
    }
    if (tid == 0) {
        float mu = s1[0] / (float)N_NODES;
        float var = s2[0] / (float)N_NODES - mu * mu;
        float sc = g[col] * rsqrtf(var + 1e-5f);
        scale[col] = sc;
        shift[col] = be[col] - mu * sc;
    }
}

// ---------------- pooling (bf16 input, u32-pair vectorized) ----------------
__global__ void k_bhist(const int* __restrict__ batch, int* __restrict__ cnt) {
    __shared__ int h[G_GRAPHS];
    int tid = threadIdx.x;
    if (tid < G_GRAPHS) h[tid] = 0;
    __syncthreads();
    int i = blockIdx.x * blockDim.x + tid;
    if (i < N_NODES) atomicAdd(&h[batch[i]], 1);
    __syncthreads();
    if (tid < G_GRAPHS) atomicAdd(&cnt[tid], h[tid]);
}

__global__ void k_pool(const u16* __restrict__ X, const int* __restrict__ batch,
                       const float* __restrict__ sc, const float* __restrict__ sh,
                       float* __restrict__ pooled) {
    int t2 = threadIdx.x;  // 192 threads, each owns u32 pair (cols 2*t2, 2*t2+1)
    const int chunk = (N_NODES + gridDim.x - 1) / gridDim.x;
    int r0 = blockIdx.x * chunk;
    int r1 = min(N_NODES, r0 + chunk);
    if (r0 >= N_NODES) return;
    float2 scv = *(const float2*)&sc[2 * t2];
    float2 shv = *(const float2*)&sh[2 * t2];
    const u32* Xw = (const u32*)X;
    float2 acc = make_float2(0.f, 0.f);
    int cur = batch[r0];
    for (int r = r0; r < r1; r++) {
        int gid = batch[r];
        if (gid != cur) {
            atomicAdd(&pooled[(size_t)cur * 384 + 2 * t2], acc.x);
            atomicAdd(&pooled[(size_t)cur * 384 + 2 * t2 + 1], acc.y);
            acc = make_float2(0.f, 0.f);
            cur = gid;
        }
        u32 u = Xw[(size_t)r * 192 + t2];
        acc.x += fmaxf(lo2f(u) * scv.x + shv.x, 0.f);
        acc.y += fmaxf(hi2f(u) * scv.y + shv.y, 0.f);
    }
    atomicAdd(&pooled[(size_t)cur * 384 + 2 * t2], acc.x);
    atomicAdd(&pooled[(size_t)cur * 384 + 2 * t2 + 1], acc.y);
}

// wave-parallel classifier: one wave per (graph, class) output
__global__ void k_final(const float* __restrict__ pooled, const int* __restrict__ cnt,
                        const float* __restrict__ lwf, const float* __restrict__ lbf,
                        float* __restrict__ out) {
    int wid = (int)((blockIdx.x * blockDim.x + threadIdx.x) >> 6);
    int lane = threadIdx.x & 63;
    if (wid >= G_GRAPHS * 10) return;
    int g = wid / 10, c = wid - g * 10;
    float inv = 1.0f / fmaxf((float)cnt[g], 1.0f);
    float acc = 0.f;
    for (int k = lane; k < 384; k += 64)
        acc += pooled[(size_t)g * 384 + k] * lwf[k * 10 + c];
#pragma unroll
    for (int off = 32; off > 0; off >>= 1) acc += __shfl_xor(acc, off);
    if (lane == 0) out[wid] = acc * inv + lbf[c];
}

extern "C" void kernel_launch(void* const* d_in, const int* in_sizes, int n_in,
                              void* d_out, int out_size, void* d_ws, size_t ws_size,
                              hipStream_t stream) {
    const float* x    = (const float*)d_in[0];
    const int*   ei   = (const int*)d_in[1];
    const int*   batch= (const int*)d_in[2];
    const float* W1   = (const float*)d_in[3];
    const float* as1  = (const float*)d_in[4];
    const float* ad1  = (const float*)d_in[5];
    const float* b1   = (const float*)d_in[6];
    const float* g1   = (const float*)d_in[7];
    const float* be1  = (const float*)d_in[8];
    const float* lw1  = (const float*)d_in[9];
    const float* lb1  = (const float*)d_in[10];
    const float* gl1  = (const float*)d_in[11];
    const float* bel1 = (const float*)d_in[12];
    const float* W2   = (const float*)d_in[13];
    const float* as2  = (const float*)d_in[14];
    const float* ad2  = (const float*)d_in[15];
    const float* b2   = (const float*)d_in[16];
    const float* g2   = (const float*)d_in[17];
    const float* be2  = (const float*)d_in[18];
    const float* lw2  = (const float*)d_in[19];
    const float* lb2  = (const float*)d_in[20];
    const float* gl2  = (const float*)d_in[21];
    const float* bel2 = (const float*)d_in[22];
    const float* W3   = (const float*)d_in[23];
    const float* as3  = (const float*)d_in[24];
    const float* ad3  = (const float*)d_in[25];
    const float* b3   = (const float*)d_in[26];
    const float* g3   = (const float*)d_in[27];
    const float* be3  = (const float*)d_in[28];
    const float* lwf  = (const float*)d_in[29];
    const float* lbf  = (const float*)d_in[30];
    float* out = (float*)d_out;

    // ---- workspace carve ----
    char* p = (char*)d_ws;
    auto alloc = [&](size_t bytes) {
        char* r = p;
        p += (bytes + 255) & ~(size_t)255;
        return r;
    };
    int*   rowptr = (int*)alloc(4 * (size_t)(N_NODES + 1));
    int*   cursor = (int*)alloc(4 * (size_t)N_NODES);
    int*   deg    = (int*)alloc(4 * (size_t)N_NODES);
    int*   bsum   = (int*)alloc(4 * (size_t)(SCAN_B + 1));
    int*   col    = (int*)alloc(4 * (size_t)TOT_E);
    int*   cdst   = (int*)alloc(4 * (size_t)TOT_E);
    float* ssrc   = (float*)alloc(4 * (size_t)N_NODES * 20);
    float* sdst   = (float*)alloc(4 * (size_t)N_NODES * 20);
    u16*   hbuf   = (u16*)alloc(2 * (size_t)N_NODES * 512);
    u16*   obuf   = (u16*)alloc(2 * (size_t)N_NODES * 512);
    u16*   xbuf   = (u16*)alloc(2 * (size_t)N_NODES * 32);
    u16*   xtil   = (u16*)alloc(2 * (size_t)N_NODES * 32);
    u8*    hbuf8  = (u8*)alloc((size_t)N_NODES * 320);
    float* psum   = (float*)alloc(4 * (size_t)PB * 512);
    float* psumsq = (float*)alloc(4 * (size_t)PB * 512);
    float* gpart  = (float*)alloc(4 * (size_t)GDB * 1024);  // gemmd partials [GDB][2*NO<=1024]
    float* scA    = (float*)alloc(4 * 512);
    float* shA    = (float*)alloc(4 * 512);
    float* scB    = (float*)alloc(4 * 64);
    float* shB    = (float*)alloc(4 * 64);
    float* wts    = (float*)alloc(4 * 256);
    float* wtd    = (float*)alloc(4 * 256);
    float* pooled = (float*)alloc(4 * (size_t)G_GRAPHS * 384);
    int*   cnt    = (int*)alloc(4 * G_GRAPHS);
    u16*   bp1    = (u16*)alloc(2 * (size_t)4 * 20 * 64 * 8);   // W1: KC=4,NT=20
    u16*   bp2    = (u16*)alloc(2 * (size_t)1 * 32 * 64 * 8);   // W2: KC=1,NT=32
    u16*   bp3    = (u16*)alloc(2 * (size_t)1 * 24 * 64 * 8);   // W3: KC=1,NT=24
    u16*   bpl1   = (u16*)alloc(2 * (size_t)10 * 1 * 64 * 8);   // lw1: KC=10,NT=1
    u16*   bpl2   = (u16*)alloc(2 * (size_t)16 * 2 * 64 * 8);   // lw2: KC=16,NT=2
    u16*   mbuf   = hbuf;  // m[N][256] bf16 aliases hbuf (free after layer 1)

    const int LB = (N_NODES + 63) / 64;   // 782 row-tiles for MFMA gemms

    // ---- graph build + W packs (reused by all 3 layers) ----
    k_init_deg<<<(N_NODES + 255) / 256, 256, 0, stream>>>(deg);
    k_hist<<<(N_EDGES + 255) / 256, 256, 0, stream>>>(ei, deg);
    k_scan1<<<SCAN_B, 512, 0, stream>>>(deg, rowptr, bsum);
    k_scan2<<<1, 128, 0, stream>>>(bsum);
    k_scan3<<<(N_NODES + 255) / 256, 256, 0, stream>>>(rowptr, cursor, bsum);
    k_scatter<<<(TOT_E + 255) / 256, 256, 0, stream>>>(ei, cursor, col, cdst);
    k_wpack<128, 320><<<20, 256, 0, stream>>>(W1, bp1);
    k_wpack<16, 512><<<8, 256, 0, stream>>>(W2, bp2);
    k_wpack<32, 384><<<6, 256, 0, stream>>>(W3, bp3);
    k_wpack<320, 16><<<3, 256, 0, stream>>>(lw1, bpl1);
    k_wpack<512, 32><<<8, 256, 0, stream>>>(lw2, bpl2);
    hipMemsetAsync(pooled, 0, 4 * (size_t)G_GRAPHS * 384 + 256, stream);  // pooled + cnt

    // ---- layer 1: GAT(128 -> 20x16) (h-gather path; fp8 shadow for the gather) ----
    k_gemm<128, 320, false><<<LB, 256, 0, stream>>>(x, bp1, nullptr, nullptr, hbuf);
    k_scores<20, 16><<<(N_NODES * 20 + 255) / 256, 256, 0, stream>>>(hbuf, as1, ad1, ssrc, sdst, hbuf8);
    k_agg8<20, 16><<<(N_NODES + 3) / 4, 256, 0, stream>>>(hbuf8, ssrc, sdst, rowptr, col, b1, obuf);
    k_bnstats<320><<<PB, 320, 0, stream>>>(obuf, psum, psumsq);
    k_bnfinal<<<320, 256, 0, stream>>>(psum, psumsq, g1, be1, scA, shA, 320);
    k_gemmb<320, 16, true, true><<<LB, 256, 0, stream>>>(obuf, bpl1, scA, shA, lb1, xbuf);
    k_bnstats<16><<<PB, 256, 0, stream>>>(xbuf, psum, psumsq);
    k_bnfinal<<<16, 256, 0, stream>>>(psum, psumsq, gl1, bel1, scB, shB, 16);

    // ---- layer 2: GAT(16 -> 16x32), aggregate-then-transform ----
    k_wtilde<16, 512, 16, 32><<<1, 256, 0, stream>>>(W2, as2, ad2, wts, wtd);
    k_xform<16><<<(N_NODES * 8 + 255) / 256, 256, 0, stream>>>(xbuf, scB, shB, xtil);
    k_scores_x<16, 16><<<(N_NODES * 16 + 255) / 256, 256, 0, stream>>>(xtil, wts, wtd, ssrc, sdst);
    k_aggx<16, 16><<<(N_NODES + 3) / 4, 256, 0, stream>>>(xtil, ssrc, sdst, rowptr, col, mbuf);
    k_gemmd<16, 512, 32><<<GDB, 256, 0, stream>>>(mbuf, bp2, b2, obuf, gpart);
    k_bnfinalg<<<512, 256, 0, stream>>>(gpart, g2, be2, scA, shA, 512, GDB);
    k_gemmb<512, 32, true, true><<<LB, 256, 0, stream>>>(obuf, bpl2, scA, shA, lb2, xbuf);
    k_bnstats<32><<<PB, 256, 0, stream>>>(xbuf, psum, psumsq);
    k_bnfinal<<<32, 256, 0, stream>>>(psum, psumsq, gl2, bel2, scB, shB, 32);

    // ---- layer 3: GAT(32 -> 8x48), aggregate-then-transform ----
    k_wtilde<32, 384, 8, 48><<<1, 256, 0, stream>>>(W3, as3, ad3, wts, wtd);
    k_xform<32><<<(N_NODES * 16 + 255) / 256, 256, 0, stream>>>(xbuf, scB, shB, xtil);
    k_scores_x<32, 8><<<(N_NODES * 8 + 255) / 256, 256, 0, stream>>>(xtil, wts, wtd, ssrc, sdst);
    k_aggx<8, 32><<<(N_NODES + 3) / 4, 256, 0, stream>>>(xtil, ssrc, sdst, rowptr, col, mbuf);
    k_gemmd<32, 384, 48><<<GDB, 256, 0, stream>>>(mbuf, bp3, b3, obuf, gpart);
    k_bnfinalg<<<384, 256, 0, stream>>>(gpart, g3, be3, scA, shA, 384, GDB);

    // ---- pool + classifier ----
    k_bhist<<<(N_NODES + 255) / 256, 256, 0, stream>>>(batch, cnt);
    k_pool<<<2048, 192, 0, stream>>>(obuf, batch, scA, shA, pooled);
    k_final<<<160, 256, 0, stream>>>(pooled, cnt, lwf, lbf, out);
}